// Round 1
// baseline (821.994 us; speedup 1.0000x reference)
//
#include <hip/hip_runtime.h>
#include <hip/hip_bf16.h>

#define LRELU(v) ((v) > 0.f ? (v) : 0.2f * (v))

// ---------------- CSR build ----------------

__global__ void k_hist(const int* __restrict__ ei, int E, int* __restrict__ cnt) {
    int e = blockIdx.x * 256 + threadIdx.x;
    if (e < E) atomicAdd(&cnt[ei[E + e]], 1);   // dst = ei[E + e]
}

// 3-phase exclusive scan over N counts (chunks of 1024)
__global__ void k_scan1(const int* __restrict__ cnt, int N, int* __restrict__ offs,
                        int* __restrict__ bsum) {
    __shared__ int wsum[4];
    int t = threadIdx.x, b = blockIdx.x;
    int base = b * 1024 + t * 4;
    int v[4];
#pragma unroll
    for (int i = 0; i < 4; i++) { int idx = base + i; v[i] = (idx < N) ? cnt[idx] : 0; }
    int tsum = v[0] + v[1] + v[2] + v[3];
    int incl = tsum;
#pragma unroll
    for (int off = 1; off < 64; off <<= 1) {
        int u = __shfl_up(incl, off);
        if ((t & 63) >= off) incl += u;
    }
    int excl = incl - tsum;
    if ((t & 63) == 63) wsum[t >> 6] = incl;
    __syncthreads();
    int wbase = 0;
    for (int w = 0; w < (t >> 6); ++w) wbase += wsum[w];
    int run = wbase + excl;
#pragma unroll
    for (int i = 0; i < 4; i++) { int idx = base + i; if (idx < N) offs[idx] = run; run += v[i]; }
    if (t == 0) bsum[b] = wsum[0] + wsum[1] + wsum[2] + wsum[3];
}

__global__ void k_scan2(int* __restrict__ bsum, int nb, int* __restrict__ offs, int N) {
    if (blockIdx.x == 0 && threadIdx.x == 0) {
        int run = 0;
        for (int b = 0; b < nb; b++) { int v = bsum[b]; bsum[b] = run; run += v; }
        offs[N] = run;
    }
}

__global__ void k_scan3(int* __restrict__ offs, int N, const int* __restrict__ bsum) {
    int add = bsum[blockIdx.x];
    int base = blockIdx.x * 1024 + threadIdx.x * 4;
#pragma unroll
    for (int i = 0; i < 4; i++) { int j = base + i; if (j < N) offs[j] += add; }
}

__global__ void k_scatter(const int* __restrict__ ei, int E, const int* __restrict__ offs,
                          int* __restrict__ cursor, int* __restrict__ csr) {
    int e = blockIdx.x * 256 + threadIdx.x;
    if (e < E) {
        int s = ei[e];
        int d = ei[E + e];
        int pos = offs[d] + atomicAdd(&cursor[d], 1);
        csr[pos] = s;
    }
}

// ---------------- Layer 1: h = x @ W1  [N,128], plus per-(n,head) alpha logits ----------------

__global__ __launch_bounds__(256) void k_gemm1(const float* __restrict__ x, const float* __restrict__ W1,
                                               const float* __restrict__ asw, const float* __restrict__ adw,
                                               float* __restrict__ h, float* __restrict__ aS,
                                               float* __restrict__ aD, int N) {
    __shared__ float Wl[64 * 128];
    __shared__ float xl[2][64];
    int t = threadIdx.x;
    for (int i = t; i < 64 * 128; i += 256) Wl[i] = W1[i];
    int n0 = blockIdx.x * 2;
    if (t < 128) {
        int r = t >> 6, k = t & 63;
        if (n0 + r < N) xl[r][k] = x[(size_t)(n0 + r) * 64 + k];
    }
    __syncthreads();
    int r = t >> 7, col = t & 127, head = col >> 5, d = col & 31;
    int n = n0 + r;
    if (n >= N) return;
    float acc = 0.f;
#pragma unroll
    for (int k = 0; k < 64; k++) acc = fmaf(xl[r][k], Wl[k * 128 + col], acc);
    h[(size_t)n * 128 + col] = acc;
    float as = acc * asw[col];   // a_src1 flat [head*32+d] == [col]
    float ad = acc * adw[col];
#pragma unroll
    for (int m = 16; m >= 1; m >>= 1) { as += __shfl_xor(as, m); ad += __shfl_xor(ad, m); }
    if (d == 0) { aS[n * 4 + head] = as; aD[n * 4 + head] = ad; }
}

// ---------------- Layer 1 attention+aggregate: online softmax over incoming edges ----------------

__global__ __launch_bounds__(256) void k_gat1(const float* __restrict__ h, const float* __restrict__ aS,
                                              const float* __restrict__ aD, const int* __restrict__ offs,
                                              const int* __restrict__ csr, const float* __restrict__ b1,
                                              float* __restrict__ out, int N) {
    int t = threadIdx.x;
    int n = blockIdx.x * 2 + (t >> 7);
    if (n >= N) return;
    int col = t & 127, head = col >> 5;
    float aDn = aD[n * 4 + head];
    float m = LRELU(aS[n * 4 + head] + aDn);   // self-loop logit
    float s = 1.f;
    float acc = h[(size_t)n * 128 + col];      // self message, weight exp(0)=1
    int beg = offs[n], end = offs[n + 1];
    for (int j = beg; j < end; ++j) {
        int src = csr[j];
        float e = LRELU(aS[src * 4 + head] + aDn);
        float hv = h[(size_t)src * 128 + col];
        if (e > m) { float sc = __expf(m - e); s *= sc; acc *= sc; m = e; }
        float w = __expf(e - m);
        s += w;
        acc = fmaf(w, hv, acc);
    }
    float o = acc / (s + 1e-16f) + b1[col];
    out[(size_t)n * 128 + col] = fmaxf(o, 0.f);
}

// ---------------- Layer 2: h2 = relu(h1) @ W2  [N,32], alpha logits (1 head) ----------------

__global__ __launch_bounds__(256) void k_gemm2(const float* __restrict__ h1r, const float* __restrict__ W2,
                                               const float* __restrict__ asw, const float* __restrict__ adw,
                                               float* __restrict__ h2, float* __restrict__ aS,
                                               float* __restrict__ aD, int N) {
    __shared__ float Wl[128 * 32];
    __shared__ float xr[8][128];
    int t = threadIdx.x;
    for (int i = t; i < 128 * 32; i += 256) Wl[i] = W2[i];
    int n0 = blockIdx.x * 8;
    for (int i = t; i < 8 * 128; i += 256) {
        int rr = i >> 7;
        if (n0 + rr < N) xr[rr][i & 127] = h1r[(size_t)(n0 + rr) * 128 + (i & 127)];
    }
    __syncthreads();
    int r = t >> 5, col = t & 31;
    int n = n0 + r;
    if (n >= N) return;
    float acc = 0.f;
#pragma unroll
    for (int k = 0; k < 128; k++) acc = fmaf(xr[r][k], Wl[k * 32 + col], acc);
    h2[(size_t)n * 32 + col] = acc;
    float as = acc * asw[col], ad = acc * adw[col];
#pragma unroll
    for (int m = 16; m >= 1; m >>= 1) { as += __shfl_xor(as, m); ad += __shfl_xor(ad, m); }
    if (col == 0) { aS[n] = as; aD[n] = ad; }
}

__global__ __launch_bounds__(256) void k_gat2(const float* __restrict__ h2, const float* __restrict__ aS,
                                              const float* __restrict__ aD, const int* __restrict__ offs,
                                              const int* __restrict__ csr, const float* __restrict__ b2,
                                              float* __restrict__ out, int N) {
    int t = threadIdx.x;
    int n = blockIdx.x * 8 + (t >> 5);
    if (n >= N) return;
    int d = t & 31;
    float aDn = aD[n];
    float m = LRELU(aS[n] + aDn);
    float s = 1.f;
    float acc = h2[(size_t)n * 32 + d];
    int beg = offs[n], end = offs[n + 1];
    for (int j = beg; j < end; ++j) {
        int src = csr[j];
        float e = LRELU(aS[src] + aDn);
        float hv = h2[(size_t)src * 32 + d];
        if (e > m) { float sc = __expf(m - e); s *= sc; acc *= sc; m = e; }
        float w = __expf(e - m);
        s += w;
        acc = fmaf(w, hv, acc);
    }
    float o = acc / (s + 1e-16f) + b2[d];
    out[(size_t)n * 32 + d] = fmaxf(o, 0.f);
}

// ---------------- Pool + classifier ----------------

__global__ void k_pool(const float* __restrict__ h2r, const int* __restrict__ batch, int N,
                       const float* __restrict__ Wc, const float* __restrict__ bc,
                       float* __restrict__ out) {
    int g = blockIdx.x;
    int t = threadIdx.x, d = t & 31, r = t >> 5;
    // lower_bound(batch, g) and lower_bound(batch, g+1)
    int lo = 0, hi = N;
    while (lo < hi) { int mid = (lo + hi) >> 1; if (batch[mid] < g) lo = mid + 1; else hi = mid; }
    int start = lo;
    hi = N;
    while (lo < hi) { int mid = (lo + hi) >> 1; if (batch[mid] < g + 1) lo = mid + 1; else hi = mid; }
    int end = lo;
    float sum = 0.f;
    for (int i = start + r; i < end; i += 2) sum += h2r[(size_t)i * 32 + d];
    sum += __shfl_xor(sum, 32);
    float cnt = (float)(end - start);
    float mean = sum / fmaxf(cnt, 1.f);
    float v = mean * Wc[d];
#pragma unroll
    for (int m = 16; m >= 1; m >>= 1) v += __shfl_xor(v, m);
    if (t == 0) out[g] = 1.f / (1.f + expf(-(v + bc[0])));
}

// ---------------- launch ----------------

extern "C" void kernel_launch(void* const* d_in, const int* in_sizes, int n_in,
                              void* d_out, int out_size, void* d_ws, size_t ws_size,
                              hipStream_t stream) {
    const float* x    = (const float*)d_in[0];
    const int*   ei   = (const int*)d_in[1];
    const int*   batch= (const int*)d_in[2];
    const float* W1   = (const float*)d_in[3];
    const float* as1  = (const float*)d_in[4];
    const float* ad1  = (const float*)d_in[5];
    const float* b1   = (const float*)d_in[6];
    const float* W2   = (const float*)d_in[7];
    const float* as2  = (const float*)d_in[8];
    const float* ad2  = (const float*)d_in[9];
    const float* b2   = (const float*)d_in[10];
    const float* Wc   = (const float*)d_in[11];
    const float* bc   = (const float*)d_in[12];

    const int N = in_sizes[0] / 64;
    const int E = in_sizes[1] / 2;
    const int G = out_size;

    size_t off = 0;
    char* base = (char*)d_ws;
    auto alloc = [&](size_t bytes) -> char* {
        char* p = base + off;
        off += (bytes + 255) & ~(size_t)255;
        return p;
    };
    int*   cursor = (int*)alloc((size_t)N * 4);
    int*   offs   = (int*)alloc((size_t)(N + 1) * 4);
    int*   bsum   = (int*)alloc(1024 * 4);
    int*   csr    = (int*)alloc((size_t)E * 4);
    float* h1     = (float*)alloc((size_t)N * 128 * 4);
    float* h1r    = (float*)alloc((size_t)N * 128 * 4);
    float* aS1    = (float*)alloc((size_t)N * 4 * 4);
    float* aD1    = (float*)alloc((size_t)N * 4 * 4);
    float* h2     = (float*)alloc((size_t)N * 32 * 4);
    float* h2r    = (float*)alloc((size_t)N * 32 * 4);
    float* aS2    = (float*)alloc((size_t)N * 4);
    float* aD2    = (float*)alloc((size_t)N * 4);
    (void)ws_size; (void)n_in;

    const int nchunks = (N + 1023) / 1024;

    // CSR build
    hipMemsetAsync(cursor, 0, (size_t)N * 4, stream);
    k_hist<<<(E + 255) / 256, 256, 0, stream>>>(ei, E, cursor);
    k_scan1<<<nchunks, 256, 0, stream>>>(cursor, N, offs, bsum);
    k_scan2<<<1, 64, 0, stream>>>(bsum, nchunks, offs, N);
    k_scan3<<<nchunks, 256, 0, stream>>>(offs, N, bsum);
    hipMemsetAsync(cursor, 0, (size_t)N * 4, stream);
    k_scatter<<<(E + 255) / 256, 256, 0, stream>>>(ei, E, offs, cursor, csr);

    // Layer 1
    k_gemm1<<<(N + 1) / 2, 256, 0, stream>>>(x, W1, as1, ad1, h1, aS1, aD1, N);
    k_gat1<<<(N + 1) / 2, 256, 0, stream>>>(h1, aS1, aD1, offs, csr, b1, h1r, N);

    // Layer 2
    k_gemm2<<<(N + 7) / 8, 256, 0, stream>>>(h1r, W2, as2, ad2, h2, aS2, aD2, N);
    k_gat2<<<(N + 7) / 8, 256, 0, stream>>>(h2, aS2, aD2, offs, csr, b2, h2r, N);

    // Pool + classify
    k_pool<<<G, 64, 0, stream>>>(h2r, batch, N, Wc, bc, d_out ? (float*)d_out : nullptr);
}

// Round 2
// 590.088 us; speedup vs baseline: 1.3930x; 1.3930x over previous
//
#include <hip/hip_runtime.h>
#include <hip/hip_bf16.h>

#define LRELU(v) ((v) > 0.f ? (v) : 0.2f * (v))

// ---------------- CSR build ----------------

__global__ void k_hist(const int* __restrict__ ei, int E, int* __restrict__ cnt) {
    int e = blockIdx.x * 256 + threadIdx.x;
    if (e < E) atomicAdd(&cnt[ei[E + e]], 1);   // dst = ei[E + e]
}

__global__ void k_scan1(const int* __restrict__ cnt, int N, int* __restrict__ offs,
                        int* __restrict__ bsum) {
    __shared__ int wsum[4];
    int t = threadIdx.x, b = blockIdx.x;
    int base = b * 1024 + t * 4;
    int v[4];
#pragma unroll
    for (int i = 0; i < 4; i++) { int idx = base + i; v[i] = (idx < N) ? cnt[idx] : 0; }
    int tsum = v[0] + v[1] + v[2] + v[3];
    int incl = tsum;
#pragma unroll
    for (int off = 1; off < 64; off <<= 1) {
        int u = __shfl_up(incl, off);
        if ((t & 63) >= off) incl += u;
    }
    int excl = incl - tsum;
    if ((t & 63) == 63) wsum[t >> 6] = incl;
    __syncthreads();
    int wbase = 0;
    for (int w = 0; w < (t >> 6); ++w) wbase += wsum[w];
    int run = wbase + excl;
#pragma unroll
    for (int i = 0; i < 4; i++) { int idx = base + i; if (idx < N) offs[idx] = run; run += v[i]; }
    if (t == 0) bsum[b] = wsum[0] + wsum[1] + wsum[2] + wsum[3];
}

__global__ void k_scan2(int* __restrict__ bsum, int nb, int* __restrict__ offs, int N) {
    if (blockIdx.x == 0 && threadIdx.x == 0) {
        int run = 0;
        for (int b = 0; b < nb; b++) { int v = bsum[b]; bsum[b] = run; run += v; }
        offs[N] = run;
    }
}

__global__ void k_scan3(int* __restrict__ offs, int N, const int* __restrict__ bsum) {
    int add = bsum[blockIdx.x];
    int base = blockIdx.x * 1024 + threadIdx.x * 4;
#pragma unroll
    for (int i = 0; i < 4; i++) { int j = base + i; if (j < N) offs[j] += add; }
}

__global__ void k_scatter(const int* __restrict__ ei, int E, const int* __restrict__ offs,
                          int* __restrict__ cursor, int* __restrict__ csr) {
    int e = blockIdx.x * 256 + threadIdx.x;
    if (e < E) {
        int s = ei[e];
        int d = ei[E + e];
        int pos = offs[d] + atomicAdd(&cursor[d], 1);
        csr[pos] = s;
    }
}

// ---------------- Layer 1 GEMM: h = x @ W1, [N,128]; 16 nodes/block ----------------

__global__ __launch_bounds__(256) void k_gemm1(const float* __restrict__ x, const float* __restrict__ W1,
                                               const float* __restrict__ asw, const float* __restrict__ adw,
                                               float* __restrict__ h, float* __restrict__ aS,
                                               float* __restrict__ aD, int N) {
    __shared__ float Wl[64 * 128];
    __shared__ float xl[16][64];
    int t = threadIdx.x;
    for (int i = t; i < 64 * 128; i += 256) Wl[i] = W1[i];
    int n0 = blockIdx.x * 16;
    for (int i = t; i < 16 * 64; i += 256) {
        int r = i >> 6;
        xl[r][i & 63] = (n0 + r < N) ? x[(size_t)(n0 + r) * 64 + (i & 63)] : 0.f;
    }
    __syncthreads();
    int col = t & 127, half = t >> 7;     // half 0: rows 0-7, half 1: rows 8-15
    int head = col >> 5, d = col & 31;
    float acc[8] = {0, 0, 0, 0, 0, 0, 0, 0};
    for (int k = 0; k < 64; k++) {
        float w = Wl[k * 128 + col];
#pragma unroll
        for (int i = 0; i < 8; i++) acc[i] = fmaf(xl[half * 8 + i][k], w, acc[i]);
    }
#pragma unroll
    for (int i = 0; i < 8; i++) {
        int n = n0 + half * 8 + i;
        if (n < N) h[(size_t)n * 128 + col] = acc[i];
    }
    float aw = asw[col], dw = adw[col];
#pragma unroll
    for (int i = 0; i < 8; i++) {
        float as = acc[i] * aw, ad = acc[i] * dw;
#pragma unroll
        for (int mm = 16; mm >= 1; mm >>= 1) { as += __shfl_xor(as, mm); ad += __shfl_xor(ad, mm); }
        int n = n0 + half * 8 + i;
        if (d == 0 && n < N) { aS[n * 4 + head] = as; aD[n * 4 + head] = ad; }
    }
}

// ---------------- Layer 1 softmax pass: per-(node,head) m,s + per-edge alpha ----------------
// One wave per node: lane = jl*4 + head, 16 edges in parallel, 4 heads.

__global__ __launch_bounds__(256) void k_attn1(const float* __restrict__ aS, const float* __restrict__ aD,
                                               const int* __restrict__ offs, const int* __restrict__ csr,
                                               float* __restrict__ alphaE, float* __restrict__ selfw, int N) {
    int t = threadIdx.x;
    int n = blockIdx.x * 4 + (t >> 6);
    if (n >= N) return;
    int lane = t & 63;
    int head = lane & 3;
    int jl = lane >> 2;
    float aDn = aD[n * 4 + head];
    int beg = offs[n], end = offs[n + 1];
    float m = -1e30f, s = 0.f;
    for (int j = beg + jl; j < end; j += 16) {
        float e = LRELU(aS[csr[j] * 4 + head] + aDn);
        if (e > m) { s *= __expf(m - e); m = e; }
        s += __expf(e - m);
    }
    if (jl == 0) {  // self-loop
        float e = LRELU(aS[n * 4 + head] + aDn);
        if (e > m) { s *= __expf(m - e); m = e; }
        s += __expf(e - m);
    }
#pragma unroll
    for (int off = 4; off < 64; off <<= 1) {   // merge 16 lanes per head (head bits preserved)
        float mo = __shfl_xor(m, off);
        float so = __shfl_xor(s, off);
        float mn = fmaxf(m, mo);
        s = s * __expf(m - mn) + so * __expf(mo - mn);
        m = mn;
    }
    float inv = 1.f / (s + 1e-16f);
    for (int j = beg + jl; j < end; j += 16) {
        float e = LRELU(aS[csr[j] * 4 + head] + aDn);
        alphaE[(size_t)j * 4 + head] = __expf(e - m) * inv;
    }
    if (jl == 0) {
        float e = LRELU(aS[n * 4 + head] + aDn);
        selfw[n * 4 + head] = __expf(e - m) * inv;
    }
}

// ---------------- Layer 1 aggregation: pure gather-FMA, branch-free ----------------

__global__ __launch_bounds__(256) void k_agg1(const float* __restrict__ h, const float* __restrict__ alphaE,
                                              const float* __restrict__ selfw, const int* __restrict__ offs,
                                              const int* __restrict__ csr, const float* __restrict__ b1,
                                              float* __restrict__ out, int N) {
    int t = threadIdx.x;
    int n = blockIdx.x * 2 + (t >> 7);
    if (n >= N) return;
    int col = t & 127, head = col >> 5;
    float acc = selfw[n * 4 + head] * h[(size_t)n * 128 + col];
    int beg = offs[n], end = offs[n + 1];
    int j = beg;
    for (; j + 3 < end; j += 4) {
        int s0 = csr[j], s1 = csr[j + 1], s2 = csr[j + 2], s3 = csr[j + 3];
        float w0 = alphaE[(size_t)j * 4 + head];
        float w1 = alphaE[(size_t)(j + 1) * 4 + head];
        float w2 = alphaE[(size_t)(j + 2) * 4 + head];
        float w3 = alphaE[(size_t)(j + 3) * 4 + head];
        float v0 = h[(size_t)s0 * 128 + col];
        float v1 = h[(size_t)s1 * 128 + col];
        float v2 = h[(size_t)s2 * 128 + col];
        float v3 = h[(size_t)s3 * 128 + col];
        acc = fmaf(w0, v0, acc); acc = fmaf(w1, v1, acc);
        acc = fmaf(w2, v2, acc); acc = fmaf(w3, v3, acc);
    }
    for (; j < end; ++j)
        acc = fmaf(alphaE[(size_t)j * 4 + head], h[(size_t)csr[j] * 128 + col], acc);
    float o = acc + b1[col];
    out[(size_t)n * 128 + col] = fmaxf(o, 0.f);
}

// ---------------- Layer 2 GEMM: h2 = relu(h1) @ W2, [N,32]; 32 nodes/block ----------------

__global__ __launch_bounds__(256) void k_gemm2(const float* __restrict__ h1r, const float* __restrict__ W2,
                                               const float* __restrict__ asw, const float* __restrict__ adw,
                                               float* __restrict__ h2, float* __restrict__ aS,
                                               float* __restrict__ aD, int N) {
    __shared__ float Wl[128 * 32];
    __shared__ float xr[32][128];
    int t = threadIdx.x;
    for (int i = t; i < 128 * 32; i += 256) Wl[i] = W2[i];
    int n0 = blockIdx.x * 32;
    for (int i = t; i < 32 * 128; i += 256) {
        int r = i >> 7, c = i & 127;
        xr[r][c] = (n0 + r < N) ? h1r[(size_t)(n0 + r) * 128 + c] : 0.f;
    }
    __syncthreads();
    int col = t & 31, grp = t >> 5;       // grp 0..7, each owns 4 rows
    float acc[4] = {0, 0, 0, 0};
    for (int k = 0; k < 128; k++) {
        float w = Wl[k * 32 + col];
#pragma unroll
        for (int i = 0; i < 4; i++) acc[i] = fmaf(xr[grp * 4 + i][k], w, acc[i]);
    }
    float aw = asw[col], dw = adw[col];
#pragma unroll
    for (int i = 0; i < 4; i++) {
        int n = n0 + grp * 4 + i;
        if (n < N) h2[(size_t)n * 32 + col] = acc[i];
        float as = acc[i] * aw, ad = acc[i] * dw;
#pragma unroll
        for (int mm = 16; mm >= 1; mm >>= 1) { as += __shfl_xor(as, mm); ad += __shfl_xor(ad, mm); }
        if (col == 0 && n < N) { aS[n] = as; aD[n] = ad; }
    }
}

// ---------------- Layer 2 softmax pass (1 head): one wave per node ----------------

__global__ __launch_bounds__(256) void k_attn2(const float* __restrict__ aS, const float* __restrict__ aD,
                                               const int* __restrict__ offs, const int* __restrict__ csr,
                                               float* __restrict__ alphaE, float* __restrict__ selfw, int N) {
    int t = threadIdx.x;
    int n = blockIdx.x * 4 + (t >> 6);
    if (n >= N) return;
    int lane = t & 63;
    float aDn = aD[n];
    int beg = offs[n], end = offs[n + 1];
    float m = -1e30f, s = 0.f;
    for (int j = beg + lane; j < end; j += 64) {
        float e = LRELU(aS[csr[j]] + aDn);
        if (e > m) { s *= __expf(m - e); m = e; }
        s += __expf(e - m);
    }
    if (lane == 0) {
        float e = LRELU(aS[n] + aDn);
        if (e > m) { s *= __expf(m - e); m = e; }
        s += __expf(e - m);
    }
#pragma unroll
    for (int off = 1; off < 64; off <<= 1) {
        float mo = __shfl_xor(m, off);
        float so = __shfl_xor(s, off);
        float mn = fmaxf(m, mo);
        s = s * __expf(m - mn) + so * __expf(mo - mn);
        m = mn;
    }
    float inv = 1.f / (s + 1e-16f);
    for (int j = beg + lane; j < end; j += 64) {
        float e = LRELU(aS[csr[j]] + aDn);
        alphaE[j] = __expf(e - m) * inv;
    }
    if (lane == 0) selfw[n] = __expf(LRELU(aS[n] + aDn) - m) * inv;
}

// ---------------- Layer 2 aggregation ----------------

__global__ __launch_bounds__(256) void k_agg2(const float* __restrict__ h2, const float* __restrict__ alphaE,
                                              const float* __restrict__ selfw, const int* __restrict__ offs,
                                              const int* __restrict__ csr, const float* __restrict__ b2,
                                              float* __restrict__ out, int N) {
    int t = threadIdx.x;
    int n = blockIdx.x * 8 + (t >> 5);
    if (n >= N) return;
    int d = t & 31;
    float acc = selfw[n] * h2[(size_t)n * 32 + d];
    int beg = offs[n], end = offs[n + 1];
    int j = beg;
    for (; j + 3 < end; j += 4) {
        int s0 = csr[j], s1 = csr[j + 1], s2 = csr[j + 2], s3 = csr[j + 3];
        float w0 = alphaE[j], w1 = alphaE[j + 1], w2 = alphaE[j + 2], w3 = alphaE[j + 3];
        float v0 = h2[(size_t)s0 * 32 + d];
        float v1 = h2[(size_t)s1 * 32 + d];
        float v2 = h2[(size_t)s2 * 32 + d];
        float v3 = h2[(size_t)s3 * 32 + d];
        acc = fmaf(w0, v0, acc); acc = fmaf(w1, v1, acc);
        acc = fmaf(w2, v2, acc); acc = fmaf(w3, v3, acc);
    }
    for (; j < end; ++j)
        acc = fmaf(alphaE[j], h2[(size_t)csr[j] * 32 + d], acc);
    float o = acc + b2[d];
    out[(size_t)n * 32 + d] = fmaxf(o, 0.f);
}

// ---------------- Pool + classifier ----------------

__global__ void k_pool(const float* __restrict__ h2r, const int* __restrict__ batch, int N,
                       const float* __restrict__ Wc, const float* __restrict__ bc,
                       float* __restrict__ out) {
    int g = blockIdx.x;
    int t = threadIdx.x, d = t & 31, r = t >> 5;
    int lo = 0, hi = N;
    while (lo < hi) { int mid = (lo + hi) >> 1; if (batch[mid] < g) lo = mid + 1; else hi = mid; }
    int start = lo;
    hi = N;
    while (lo < hi) { int mid = (lo + hi) >> 1; if (batch[mid] < g + 1) lo = mid + 1; else hi = mid; }
    int end = lo;
    float sum = 0.f;
    for (int i = start + r; i < end; i += 2) sum += h2r[(size_t)i * 32 + d];
    sum += __shfl_xor(sum, 32);
    float cnt = (float)(end - start);
    float mean = sum / fmaxf(cnt, 1.f);
    float v = mean * Wc[d];
#pragma unroll
    for (int m = 16; m >= 1; m >>= 1) v += __shfl_xor(v, m);
    if (t == 0) out[g] = 1.f / (1.f + expf(-(v + bc[0])));
}

// ---------------- launch ----------------

extern "C" void kernel_launch(void* const* d_in, const int* in_sizes, int n_in,
                              void* d_out, int out_size, void* d_ws, size_t ws_size,
                              hipStream_t stream) {
    const float* x    = (const float*)d_in[0];
    const int*   ei   = (const int*)d_in[1];
    const int*   batch= (const int*)d_in[2];
    const float* W1   = (const float*)d_in[3];
    const float* as1  = (const float*)d_in[4];
    const float* ad1  = (const float*)d_in[5];
    const float* b1   = (const float*)d_in[6];
    const float* W2   = (const float*)d_in[7];
    const float* as2  = (const float*)d_in[8];
    const float* ad2  = (const float*)d_in[9];
    const float* b2   = (const float*)d_in[10];
    const float* Wc   = (const float*)d_in[11];
    const float* bc   = (const float*)d_in[12];

    const int N = in_sizes[0] / 64;
    const int E = in_sizes[1] / 2;
    const int G = out_size;

    size_t off = 0;
    char* base = (char*)d_ws;
    auto alloc = [&](size_t bytes) -> char* {
        char* p = base + off;
        off += (bytes + 255) & ~(size_t)255;
        return p;
    };
    int*   cursor  = (int*)alloc((size_t)N * 4);
    int*   offs    = (int*)alloc((size_t)(N + 1) * 4);
    int*   bsum    = (int*)alloc(1024 * 4);
    int*   csr     = (int*)alloc((size_t)E * 4);
    float* h1      = (float*)alloc((size_t)N * 128 * 4);      // layer-1 features
    float* h1r     = (float*)alloc((size_t)N * 128 * 4);      // relu(layer-1 out)
    float* aS1     = (float*)alloc((size_t)N * 4 * 4);
    float* aD1     = (float*)alloc((size_t)N * 4 * 4);
    float* alphaE1 = (float*)alloc((size_t)E * 4 * 4);        // [E][4] edge weights
    float* selfw1  = (float*)alloc((size_t)N * 4 * 4);
    // layer-2 buffers alias h1 (free after k_agg1 consumed it)
    char*  l2base  = (char*)h1;
    float* h2      = (float*)(l2base);                         // N*32*4 = 12.8MB
    float* h2r     = (float*)(l2base + (size_t)N * 32 * 4);
    float* aS2     = (float*)(l2base + (size_t)N * 64 * 4);
    float* aD2     = (float*)(l2base + (size_t)N * 65 * 4);
    float* alphaE2 = (float*)(l2base + (size_t)N * 66 * 4);    // E*4 = 6.4MB (N*66..N*82)
    float* selfw2  = (float*)(l2base + (size_t)N * 88 * 4);
    (void)ws_size; (void)n_in;

    const int nchunks = (N + 1023) / 1024;

    // CSR build (by dst)
    hipMemsetAsync(cursor, 0, (size_t)N * 4, stream);
    k_hist<<<(E + 255) / 256, 256, 0, stream>>>(ei, E, cursor);
    k_scan1<<<nchunks, 256, 0, stream>>>(cursor, N, offs, bsum);
    k_scan2<<<1, 64, 0, stream>>>(bsum, nchunks, offs, N);
    k_scan3<<<nchunks, 256, 0, stream>>>(offs, N, bsum);
    hipMemsetAsync(cursor, 0, (size_t)N * 4, stream);
    k_scatter<<<(E + 255) / 256, 256, 0, stream>>>(ei, E, offs, cursor, csr);

    // Layer 1
    k_gemm1<<<(N + 15) / 16, 256, 0, stream>>>(x, W1, as1, ad1, h1, aS1, aD1, N);
    k_attn1<<<(N + 3) / 4, 256, 0, stream>>>(aS1, aD1, offs, csr, alphaE1, selfw1, N);
    k_agg1<<<(N + 1) / 2, 256, 0, stream>>>(h1, alphaE1, selfw1, offs, csr, b1, h1r, N);

    // Layer 2 (h1 no longer needed -> aliased buffers)
    k_gemm2<<<(N + 31) / 32, 256, 0, stream>>>(h1r, W2, as2, ad2, h2, aS2, aD2, N);
    k_attn2<<<(N + 3) / 4, 256, 0, stream>>>(aS2, aD2, offs, csr, alphaE2, selfw2, N);
    k_agg2<<<(N + 7) / 8, 256, 0, stream>>>(h2, alphaE2, selfw2, offs, csr, b2, h2r, N);

    // Pool + classify
    k_pool<<<G, 64, 0, stream>>>(h2r, batch, N, Wc, bc, (float*)d_out);
}

// Round 3
// 511.651 us; speedup vs baseline: 1.6066x; 1.1533x over previous
//
#include <hip/hip_runtime.h>
#include <hip/hip_bf16.h>

#define LRELU(v) ((v) > 0.f ? (v) : 0.2f * (v))

__device__ inline float bf_lo(unsigned u) { return __uint_as_float(u << 16); }
__device__ inline float bf_hi(unsigned u) { return __uint_as_float(u & 0xffff0000u); }

// ---------------- CSR build ----------------

__global__ void k_hist(const int* __restrict__ ei, int E, int* __restrict__ cnt) {
    int e = blockIdx.x * 256 + threadIdx.x;
    if (e < E) atomicAdd(&cnt[ei[E + e]], 1);   // dst = ei[E + e]
}

__global__ void k_scan1(const int* __restrict__ cnt, int N, int* __restrict__ offs,
                        int* __restrict__ bsum) {
    __shared__ int wsum[4];
    int t = threadIdx.x, b = blockIdx.x;
    int base = b * 1024 + t * 4;
    int v[4];
#pragma unroll
    for (int i = 0; i < 4; i++) { int idx = base + i; v[i] = (idx < N) ? cnt[idx] : 0; }
    int tsum = v[0] + v[1] + v[2] + v[3];
    int incl = tsum;
#pragma unroll
    for (int off = 1; off < 64; off <<= 1) {
        int u = __shfl_up(incl, off);
        if ((t & 63) >= off) incl += u;
    }
    int excl = incl - tsum;
    if ((t & 63) == 63) wsum[t >> 6] = incl;
    __syncthreads();
    int wbase = 0;
    for (int w = 0; w < (t >> 6); ++w) wbase += wsum[w];
    int run = wbase + excl;
#pragma unroll
    for (int i = 0; i < 4; i++) { int idx = base + i; if (idx < N) offs[idx] = run; run += v[i]; }
    if (t == 0) bsum[b] = wsum[0] + wsum[1] + wsum[2] + wsum[3];
}

__global__ void k_scan2(int* __restrict__ bsum, int nb, int* __restrict__ offs, int N) {
    if (blockIdx.x == 0 && threadIdx.x == 0) {
        int run = 0;
        for (int b = 0; b < nb; b++) { int v = bsum[b]; bsum[b] = run; run += v; }
        offs[N] = run;
    }
}

__global__ void k_scan3(int* __restrict__ offs, int N, const int* __restrict__ bsum) {
    int add = bsum[blockIdx.x];
    int base = blockIdx.x * 1024 + threadIdx.x * 4;
#pragma unroll
    for (int i = 0; i < 4; i++) { int j = base + i; if (j < N) offs[j] += add; }
}

__global__ void k_scatter(const int* __restrict__ ei, int E, const int* __restrict__ offs,
                          int* __restrict__ cursor, int* __restrict__ csr) {
    int e = blockIdx.x * 256 + threadIdx.x;
    if (e < E) {
        int s = ei[e];
        int d = ei[E + e];
        int pos = offs[d] + atomicAdd(&cursor[d], 1);
        csr[pos] = s;
    }
}

// ---------------- Layer 1 GEMM: hb = bf16(x @ W1), [N,128]; 16 nodes/block ----------------

__global__ __launch_bounds__(256) void k_gemm1(const float* __restrict__ x, const float* __restrict__ W1,
                                               const float* __restrict__ asw, const float* __restrict__ adw,
                                               __hip_bfloat16* __restrict__ hb, float* __restrict__ aS,
                                               float* __restrict__ aD, int N) {
    __shared__ float Wl[64 * 128];
    __shared__ float xl[16][64];
    int t = threadIdx.x;
    for (int i = t; i < 64 * 128; i += 256) Wl[i] = W1[i];
    int n0 = blockIdx.x * 16;
    for (int i = t; i < 16 * 64; i += 256) {
        int r = i >> 6;
        xl[r][i & 63] = (n0 + r < N) ? x[(size_t)(n0 + r) * 64 + (i & 63)] : 0.f;
    }
    __syncthreads();
    int col = t & 127, half = t >> 7;
    int head = col >> 5, d = col & 31;
    float acc[8] = {0, 0, 0, 0, 0, 0, 0, 0};
    for (int k = 0; k < 64; k++) {
        float w = Wl[k * 128 + col];
#pragma unroll
        for (int i = 0; i < 8; i++) acc[i] = fmaf(xl[half * 8 + i][k], w, acc[i]);
    }
#pragma unroll
    for (int i = 0; i < 8; i++) {
        int n = n0 + half * 8 + i;
        if (n < N) hb[(size_t)n * 128 + col] = __float2bfloat16(acc[i]);
    }
    float aw = asw[col], dw = adw[col];
#pragma unroll
    for (int i = 0; i < 8; i++) {
        float as = acc[i] * aw, ad = acc[i] * dw;
#pragma unroll
        for (int mm = 16; mm >= 1; mm >>= 1) { as += __shfl_xor(as, mm); ad += __shfl_xor(ad, mm); }
        int n = n0 + half * 8 + i;
        if (d == 0 && n < N) { aS[n * 4 + head] = as; aD[n * 4 + head] = ad; }
    }
}

// ---------------- Layer 1 fused softmax+aggregate: one wave per node ----------------
// Phase 1: lane = slot*4+head (16 edge slots x 4 heads), online (m,s), shfl merge.
// Phase 2: lane = head*16+pair (4 heads x 16 bf16-pairs = 128 dims), branch-free gather-FMA.

__global__ __launch_bounds__(256) void k_gat1(const __hip_bfloat16* __restrict__ hb,
                                              const float* __restrict__ aS, const float* __restrict__ aD,
                                              const int* __restrict__ offs, const int* __restrict__ csr,
                                              const float* __restrict__ b1, float* __restrict__ out, int N) {
    int t = threadIdx.x;
    int n = blockIdx.x * 4 + (t >> 6);
    if (n >= N) return;                       // no barriers in this kernel
    int lane = t & 63;
    int head1 = lane & 3, slot = lane >> 2;
    float aDn1 = aD[n * 4 + head1];
    float e_self = LRELU(aS[n * 4 + head1] + aDn1);
    int beg = offs[n], end = offs[n + 1];
    float m = -1e30f, s = 0.f;
    if (slot == 0) { m = e_self; s = 1.f; }
    for (int j = beg + slot; j < end; j += 16) {
        float e = LRELU(aS[csr[j] * 4 + head1] + aDn1);
        if (e > m) { s *= __expf(m - e); m = e; }
        s += __expf(e - m);
    }
#pragma unroll
    for (int off = 4; off < 64; off <<= 1) {  // merge 16 slots per head
        float mo = __shfl_xor(m, off), so = __shfl_xor(s, off);
        float mn = fmaxf(m, mo);
        s = s * __expf(m - mn) + so * __expf(mo - mn);
        m = mn;
    }
    // redistribute to phase-2 layout: head2 = lane>>4 (lanes 0..3 hold heads 0..3)
    int head2 = lane >> 4;
    float mf   = __shfl(m, head2);
    float inv  = 1.f / (__shfl(s, head2) + 1e-16f);
    float aDn2 = __shfl(aDn1, head2);
    float es2  = __shfl(e_self, head2);

    const unsigned* hv = (const unsigned*)hb;            // [N][64] bf16-pairs
    unsigned us = hv[(size_t)n * 64 + lane];
    float w_self = __expf(es2 - mf);
    float accx = w_self * bf_lo(us), accy = w_self * bf_hi(us);

    int j = beg;
    for (; j + 3 < end; j += 4) {
        int s0 = csr[j], s1 = csr[j + 1], s2 = csr[j + 2], s3 = csr[j + 3];
        float w0 = __expf(LRELU(aS[s0 * 4 + head2] + aDn2) - mf);
        float w1 = __expf(LRELU(aS[s1 * 4 + head2] + aDn2) - mf);
        float w2 = __expf(LRELU(aS[s2 * 4 + head2] + aDn2) - mf);
        float w3 = __expf(LRELU(aS[s3 * 4 + head2] + aDn2) - mf);
        unsigned u0 = hv[(size_t)s0 * 64 + lane];
        unsigned u1 = hv[(size_t)s1 * 64 + lane];
        unsigned u2 = hv[(size_t)s2 * 64 + lane];
        unsigned u3 = hv[(size_t)s3 * 64 + lane];
        accx = fmaf(w0, bf_lo(u0), accx); accy = fmaf(w0, bf_hi(u0), accy);
        accx = fmaf(w1, bf_lo(u1), accx); accy = fmaf(w1, bf_hi(u1), accy);
        accx = fmaf(w2, bf_lo(u2), accx); accy = fmaf(w2, bf_hi(u2), accy);
        accx = fmaf(w3, bf_lo(u3), accx); accy = fmaf(w3, bf_hi(u3), accy);
    }
    for (; j < end; ++j) {
        int sj = csr[j];
        float w = __expf(LRELU(aS[sj * 4 + head2] + aDn2) - mf);
        unsigned u = hv[(size_t)sj * 64 + lane];
        accx = fmaf(w, bf_lo(u), accx); accy = fmaf(w, bf_hi(u), accy);
    }
    float2 b = ((const float2*)b1)[lane];
    float2 o;
    o.x = fmaxf(fmaf(accx, inv, b.x), 0.f);
    o.y = fmaxf(fmaf(accy, inv, b.y), 0.f);
    ((float2*)out)[(size_t)n * 64 + lane] = o;
}

// ---------------- Layer 2 GEMM: hb2 = bf16(relu(h1) @ W2), [N,32]; 32 nodes/block ----------------

__global__ __launch_bounds__(256) void k_gemm2(const float* __restrict__ h1r, const float* __restrict__ W2,
                                               const float* __restrict__ asw, const float* __restrict__ adw,
                                               __hip_bfloat16* __restrict__ hb2, float* __restrict__ aS,
                                               float* __restrict__ aD, int N) {
    __shared__ float Wl[128 * 32];
    __shared__ float xr[32][128];
    int t = threadIdx.x;
    for (int i = t; i < 128 * 32; i += 256) Wl[i] = W2[i];
    int n0 = blockIdx.x * 32;
    for (int i = t; i < 32 * 128; i += 256) {
        int r = i >> 7, c = i & 127;
        xr[r][c] = (n0 + r < N) ? h1r[(size_t)(n0 + r) * 128 + c] : 0.f;
    }
    __syncthreads();
    int col = t & 31, grp = t >> 5;
    float acc[4] = {0, 0, 0, 0};
    for (int k = 0; k < 128; k++) {
        float w = Wl[k * 32 + col];
#pragma unroll
        for (int i = 0; i < 4; i++) acc[i] = fmaf(xr[grp * 4 + i][k], w, acc[i]);
    }
    float aw = asw[col], dw = adw[col];
#pragma unroll
    for (int i = 0; i < 4; i++) {
        int n = n0 + grp * 4 + i;
        if (n < N) hb2[(size_t)n * 32 + col] = __float2bfloat16(acc[i]);
        float as = acc[i] * aw, ad = acc[i] * dw;
#pragma unroll
        for (int mm = 16; mm >= 1; mm >>= 1) { as += __shfl_xor(as, mm); ad += __shfl_xor(ad, mm); }
        if (col == 0 && n < N) { aS[n] = as; aD[n] = ad; }
    }
}

// ---------------- Layer 2 fused softmax+aggregate: one wave per node, 1 head ----------------
// Phase 1: 64 edge slots. Phase 2: 4 edges x 16 bf16-pairs (32 dims), shfl-reduce groups.

__global__ __launch_bounds__(256) void k_gat2(const __hip_bfloat16* __restrict__ hb,
                                              const float* __restrict__ aS, const float* __restrict__ aD,
                                              const int* __restrict__ offs, const int* __restrict__ csr,
                                              const float* __restrict__ b2, float* __restrict__ out, int N) {
    int t = threadIdx.x;
    int n = blockIdx.x * 4 + (t >> 6);
    if (n >= N) return;
    int lane = t & 63;
    float aDn = aD[n];
    float e_self = LRELU(aS[n] + aDn);
    int beg = offs[n], end = offs[n + 1];
    float m = (lane == 0) ? e_self : -1e30f;
    float s = (lane == 0) ? 1.f : 0.f;
    for (int j = beg + lane; j < end; j += 64) {
        float e = LRELU(aS[csr[j]] + aDn);
        if (e > m) { s *= __expf(m - e); m = e; }
        s += __expf(e - m);
    }
#pragma unroll
    for (int off = 1; off < 64; off <<= 1) {
        float mo = __shfl_xor(m, off), so = __shfl_xor(s, off);
        float mn = fmaxf(m, mo);
        s = s * __expf(m - mn) + so * __expf(mo - mn);
        m = mn;
    }
    float inv = 1.f / (s + 1e-16f);

    int e4 = lane >> 4, pair = lane & 15;
    const unsigned* hv = (const unsigned*)hb;   // [N][16] bf16-pairs
    float accx = 0.f, accy = 0.f;
    if (e4 == 0) {
        float w = __expf(e_self - m);
        unsigned u = hv[(size_t)n * 16 + pair];
        accx = w * bf_lo(u); accy = w * bf_hi(u);
    }
    for (int j = beg; j < end; j += 4) {
        int jj = j + e4;
        bool v = jj < end;
        int src = v ? csr[jj] : n;
        float w = v ? __expf(LRELU(aS[src] + aDn) - m) : 0.f;
        unsigned u = hv[(size_t)src * 16 + pair];
        accx = fmaf(w, bf_lo(u), accx);
        accy = fmaf(w, bf_hi(u), accy);
    }
    accx += __shfl_xor(accx, 16); accy += __shfl_xor(accy, 16);
    accx += __shfl_xor(accx, 32); accy += __shfl_xor(accy, 32);
    if (e4 == 0) {
        float2 b = ((const float2*)b2)[pair];
        float2 o;
        o.x = fmaxf(fmaf(accx, inv, b.x), 0.f);
        o.y = fmaxf(fmaf(accy, inv, b.y), 0.f);
        ((float2*)out)[(size_t)n * 16 + pair] = o;
    }
}

// ---------------- Pool + classifier ----------------

__global__ void k_pool(const float* __restrict__ h2r, const int* __restrict__ batch, int N,
                       const float* __restrict__ Wc, const float* __restrict__ bc,
                       float* __restrict__ out) {
    int g = blockIdx.x;
    int t = threadIdx.x, d = t & 31, r = t >> 5;
    int lo = 0, hi = N;
    while (lo < hi) { int mid = (lo + hi) >> 1; if (batch[mid] < g) lo = mid + 1; else hi = mid; }
    int start = lo;
    hi = N;
    while (lo < hi) { int mid = (lo + hi) >> 1; if (batch[mid] < g + 1) lo = mid + 1; else hi = mid; }
    int end = lo;
    float sum = 0.f;
    for (int i = start + r; i < end; i += 2) sum += h2r[(size_t)i * 32 + d];
    sum += __shfl_xor(sum, 32);
    float cnt = (float)(end - start);
    float mean = sum / fmaxf(cnt, 1.f);
    float v = mean * Wc[d];
#pragma unroll
    for (int m = 16; m >= 1; m >>= 1) v += __shfl_xor(v, m);
    if (t == 0) out[g] = 1.f / (1.f + expf(-(v + bc[0])));
}

// ---------------- launch ----------------

extern "C" void kernel_launch(void* const* d_in, const int* in_sizes, int n_in,
                              void* d_out, int out_size, void* d_ws, size_t ws_size,
                              hipStream_t stream) {
    const float* x    = (const float*)d_in[0];
    const int*   ei   = (const int*)d_in[1];
    const int*   batch= (const int*)d_in[2];
    const float* W1   = (const float*)d_in[3];
    const float* as1  = (const float*)d_in[4];
    const float* ad1  = (const float*)d_in[5];
    const float* b1   = (const float*)d_in[6];
    const float* W2   = (const float*)d_in[7];
    const float* as2  = (const float*)d_in[8];
    const float* ad2  = (const float*)d_in[9];
    const float* b2   = (const float*)d_in[10];
    const float* Wc   = (const float*)d_in[11];
    const float* bc   = (const float*)d_in[12];

    const int N = in_sizes[0] / 64;
    const int E = in_sizes[1] / 2;
    const int G = out_size;

    size_t off = 0;
    char* base = (char*)d_ws;
    auto alloc = [&](size_t bytes) -> char* {
        char* p = base + off;
        off += (bytes + 255) & ~(size_t)255;
        return p;
    };
    int*   cursor = (int*)alloc((size_t)N * 4);
    int*   offs   = (int*)alloc((size_t)(N + 1) * 4);
    int*   bsum   = (int*)alloc(1024 * 4);
    int*   csr    = (int*)alloc((size_t)E * 4);
    __hip_bfloat16* hb1 = (__hip_bfloat16*)alloc((size_t)N * 128 * 2);
    float* h1r    = (float*)alloc((size_t)N * 128 * 4);
    float* aS1    = (float*)alloc((size_t)N * 4 * 4);
    float* aD1    = (float*)alloc((size_t)N * 4 * 4);
    __hip_bfloat16* hb2 = (__hip_bfloat16*)alloc((size_t)N * 32 * 2);
    float* h2r    = (float*)alloc((size_t)N * 32 * 4);
    float* aS2    = (float*)alloc((size_t)N * 4);
    float* aD2    = (float*)alloc((size_t)N * 4);
    (void)ws_size; (void)n_in;

    const int nchunks = (N + 1023) / 1024;

    // CSR build (by dst)
    hipMemsetAsync(cursor, 0, (size_t)N * 4, stream);
    k_hist<<<(E + 255) / 256, 256, 0, stream>>>(ei, E, cursor);
    k_scan1<<<nchunks, 256, 0, stream>>>(cursor, N, offs, bsum);
    k_scan2<<<1, 64, 0, stream>>>(bsum, nchunks, offs, N);
    k_scan3<<<nchunks, 256, 0, stream>>>(offs, N, bsum);
    hipMemsetAsync(cursor, 0, (size_t)N * 4, stream);
    k_scatter<<<(E + 255) / 256, 256, 0, stream>>>(ei, E, offs, cursor, csr);

    // Layer 1
    k_gemm1<<<(N + 15) / 16, 256, 0, stream>>>(x, W1, as1, ad1, hb1, aS1, aD1, N);
    k_gat1<<<(N + 3) / 4, 256, 0, stream>>>(hb1, aS1, aD1, offs, csr, b1, h1r, N);

    // Layer 2
    k_gemm2<<<(N + 31) / 32, 256, 0, stream>>>(h1r, W2, as2, ad2, hb2, aS2, aD2, N);
    k_gat2<<<(N + 3) / 4, 256, 0, stream>>>(hb2, aS2, aD2, offs, csr, b2, h2r, N);

    // Pool + classify
    k_pool<<<G, 64, 0, stream>>>(h2r, batch, N, Wc, bc, (float*)d_out);
}